// Round 9
// baseline (369.391 us; speedup 1.0000x reference)
//
#include <hip/hip_runtime.h>
#include <hip/hip_bf16.h>
#include <stdint.h>

typedef __bf16 bf16_t;
typedef __bf16 bf16x4 __attribute__((ext_vector_type(4)));
typedef __bf16 bf16x8 __attribute__((ext_vector_type(8)));
typedef float  f32x4  __attribute__((ext_vector_type(4)));
typedef float  f32x16 __attribute__((ext_vector_type(16)));
typedef unsigned int u32;

#define B_  4
#define L_  2048
#define D_  1024
#define H_  16
#define DH_ 64

// async global->LDS, 16B per lane. lds ptr is wave-uniform; HW adds lane*16.
__device__ __forceinline__ void async_load16(const bf16_t* g, bf16_t* lds) {
    __builtin_amdgcn_global_load_lds(
        (__attribute__((address_space(1))) void*)g,
        (__attribute__((address_space(3))) void*)lds, 16, 0, 0);
}

// All fp32->bf16 conversions in ONE launch: 3 activations (2^21 float4 each)
// then 4 weights (2^18 float4 each). 7,340,032 float4s = 28672 blocks.
__global__ __launch_bounds__(256) void cvt_all(
    const float* __restrict__ a0, const float* __restrict__ a1,
    const float* __restrict__ a2,
    const float* __restrict__ w0, const float* __restrict__ w1,
    const float* __restrict__ w2, const float* __restrict__ w3,
    bf16_t* __restrict__ oa0, bf16_t* __restrict__ oa1, bf16_t* __restrict__ oa2,
    bf16_t* __restrict__ ow0, bf16_t* __restrict__ ow1,
    bf16_t* __restrict__ ow2, bf16_t* __restrict__ ow3)
{
    int i = blockIdx.x * 256 + threadIdx.x;
    const float* src; bf16_t* dst; size_t j;
    if (i < 3 * (1 << 21)) {
        int which = i >> 21;
        src = which == 0 ? a0 : which == 1 ? a1 : a2;
        dst = which == 0 ? oa0 : which == 1 ? oa1 : oa2;
        j = (size_t)(i & ((1 << 21) - 1)) * 4;
    } else {
        int k = i - 3 * (1 << 21);
        int which = k >> 18;
        src = which == 0 ? w0 : which == 1 ? w1 : which == 2 ? w2 : w3;
        dst = which == 0 ? ow0 : which == 1 ? ow1 : which == 2 ? ow2 : ow3;
        j = (size_t)(k & ((1 << 18) - 1)) * 4;
    }
    f32x4 v = *(const f32x4*)(src + j);
    bf16x4 ov;
    ov[0] = (bf16_t)v[0]; ov[1] = (bf16_t)v[1];
    ov[2] = (bf16_t)v[2]; ov[3] = (bf16_t)v[3];
    *(bf16x4*)(dst + j) = ov;
}

// ---------------------------------------------------------------------------
// C[M,1024] = A[M,1024] * B[1024,1024]^T, bf16 in, fp32 accum.
// 128x128 tile, 4 waves (2x2 of 64x64), 32x32x16 bf16 MFMA, BK=64.
//
// L2-FOOTPRINT SCHEDULING (R9): blocks are pinned to XCDs (flat id % 8 = XCD)
// and each XCD's resident set is kept to ONE z-slice's working set:
//   block (j = blockIdx.x, g = blockIdx.y) -> tile row 8j + g/8, col g%8.
// QKV runs 512 PERSISTENT blocks (exactly 2/CU), looping z=0,1,2. At any
// instant XCD j's 64 blocks touch 8 A-panels (2MB) + one B (2MB) = 4MB = L2.
// Previously (z-fused grid, ~5 blocks/CU) the co-resident footprint was
// 3 z x 4MB = 12MB -> L2 thrash -> ~6x HBM/L3 over-fetch, GEMMs ~400 TF.
//
// Layout facts (guide m74/m101, validated by attn R4+): 32x32x16_bf16:
//   A: row=lane&31, k=(lane>>5)*8+j ; B: col=lane&31, k=(lane>>5)*8+j
//   C: col=lane&31, row=(reg&3)+8*(reg>>2)+4*(lane>>5)
//
// mode 0: bf16 row-major out. mode 2: fp32 row-major out (final projection).
// ---------------------------------------------------------------------------
__device__ __forceinline__ void stage_ab(
    const bf16_t* __restrict__ A, const bf16_t* __restrict__ Bm,
    bf16_t* lds, int rowBase, int colBase, int k0, int t)
{
    const int wbase = t & ~63;             // wave-uniform LDS base component
    #pragma unroll
    for (int sweep = 0; sweep < 4; ++sweep) {
        int c = sweep * 256 + t;           // 16B chunk id, 0..1023
        int r = c >> 3, kc = c & 7;        // row (128B = 8 chunks/row)
        int kcs = kc ^ (r & 7);            // pre-swizzled global source chunk
        async_load16(&A[((size_t)(rowBase + r) << 10) + k0 + kcs * 8],
                     &lds[(sweep * 256 + wbase) * 8]);
        async_load16(&Bm[((size_t)(colBase + r) << 10) + k0 + kcs * 8],
                     &lds[8192 + (sweep * 256 + wbase) * 8]);
    }
}

__device__ __forceinline__ void gemm_tile(
    const bf16_t* __restrict__ A, const bf16_t* __restrict__ Bm,
    bf16_t* __restrict__ Cb, float* __restrict__ Cf,
    int mode, bf16_t* lds, int rowBase, int colBase)
{
    const int t = threadIdx.x;
    const int w = t >> 6, l = t & 63;
    const int l31 = l & 31, hi = l >> 5;
    const int wm = w >> 1, wn = w & 1;

    f32x16 acc[2][2] = {};   // [mf][nf], 32x32 frags

    for (int k0 = 0; k0 < 1024; k0 += 64) {
        stage_ab(A, Bm, lds, rowBase, colBase, k0, t);
        __syncthreads();     // drains vmcnt -> tile visible

        #pragma unroll
        for (int ks = 0; ks < 4; ++ks) {
            int g = ks * 2 + hi;           // 16B chunk of this k16-step
            bf16x8 af[2], bg[2];
            #pragma unroll
            for (int mf = 0; mf < 2; ++mf) {
                int row = wm * 64 + mf * 32 + l31;
                af[mf] = *(const bf16x8*)&lds[row * 64 + ((g ^ (row & 7)) * 8)];
            }
            #pragma unroll
            for (int nfi = 0; nfi < 2; ++nfi) {
                int row = wn * 64 + nfi * 32 + l31;
                bg[nfi] = *(const bf16x8*)&lds[8192 + row * 64 + ((g ^ (row & 7)) * 8)];
            }
            #pragma unroll
            for (int mf = 0; mf < 2; ++mf)
                #pragma unroll
                for (int nfi = 0; nfi < 2; ++nfi)
                    acc[mf][nfi] = __builtin_amdgcn_mfma_f32_32x32x16_bf16(
                        af[mf], bg[nfi], acc[mf][nfi], 0, 0, 0);
        }
        __syncthreads();     // all reads done before next-tile overwrite
    }

    #pragma unroll
    for (int mf = 0; mf < 2; ++mf)
        #pragma unroll
        for (int nfi = 0; nfi < 2; ++nfi)
            #pragma unroll
            for (int reg = 0; reg < 16; ++reg) {
                int row = rowBase + wm * 64 + mf * 32
                        + (reg & 3) + 8 * (reg >> 2) + 4 * hi;
                int col = colBase + wn * 64 + nfi * 32 + l31;
                float v = acc[mf][nfi][reg];
                if (mode == 0) {
                    Cb[((size_t)row << 10) + col] = (bf16_t)v;
                } else {
                    Cf[((size_t)row << 10) + col] = v;
                }
            }
}

// Final projection: 512 blocks, one tile each, XCD-pinned row-grouped mapping.
__global__ __launch_bounds__(256) void gemm_bt(
    const bf16_t* __restrict__ A, const bf16_t* __restrict__ Bm,
    bf16_t* __restrict__ Cb, float* __restrict__ Cf, int mode)
{
    __shared__ __align__(16) bf16_t lds[16384];   // A 16KB | B 16KB
    const int j = blockIdx.x;                     // XCD (flat id % 8)
    const int g = blockIdx.y;                     // 0..63 within XCD
    const int rowBase = (8 * j + (g >> 3)) * 128;
    const int colBase = (g & 7) * 128;
    gemm_tile(A, Bm, Cb, Cf, mode, lds, rowBase, colBase);
}

// QKV projections: 512 PERSISTENT blocks (2/CU), each does its tile for
// z = 0 (Q), 1 (K), 2 (V row-major) in sequence. Per-XCD instantaneous
// footprint = one z's 8 A-panels + B = 4MB = L2. No extra barrier between
// z's: the K-loop's final __syncthreads precedes the register-only epilogue,
// so next-z staging cannot race any LDS reader.
__global__ __launch_bounds__(256) void gemm_qkv(
    const bf16_t* __restrict__ A0, const bf16_t* __restrict__ B0, bf16_t* __restrict__ C0,
    const bf16_t* __restrict__ A1, const bf16_t* __restrict__ B1, bf16_t* __restrict__ C1,
    const bf16_t* __restrict__ A2, const bf16_t* __restrict__ B2, bf16_t* __restrict__ C2)
{
    __shared__ __align__(16) bf16_t lds[16384];
    const int j = blockIdx.x;                     // XCD (flat id % 8)
    const int g = blockIdx.y;                     // 0..63 within XCD
    const int rowBase = (8 * j + (g >> 3)) * 128;
    const int colBase = (g & 7) * 128;
    #pragma unroll 1
    for (int z = 0; z < 3; ++z) {
        const bf16_t* A  = z == 0 ? A0 : z == 1 ? A1 : A2;
        const bf16_t* Bm = z == 0 ? B0 : z == 1 ? B1 : B2;
        bf16_t*       C  = z == 0 ? C0 : z == 1 ? C1 : C2;
        gemm_tile(A, Bm, C, nullptr, 0, lds, rowBase, colBase);
    }
}

// ---------------------------------------------------------------------------
// V row-major [B*L][1024] -> Vt[B][H][64][2048], via 64x64 LDS tiles.
// Both global read and write fully coalesced (16B/lane). 2048 blocks.
// ---------------------------------------------------------------------------
__global__ __launch_bounds__(256) void transpose_v(
    const bf16_t* __restrict__ Vr, bf16_t* __restrict__ Vt)
{
    __shared__ __align__(16) bf16_t T[64][72];   // T[d][s], padded rows
    const int t = threadIdx.x;
    const int st = blockIdx.x;                   // s-tile 0..31
    const int h = blockIdx.y, b = blockIdx.z;

    #pragma unroll
    for (int k = 0; k < 2; ++k) {
        int c = k * 256 + t;                     // 0..511
        int s = c >> 3, dch = c & 7;             // row s, 16B d-chunk
        bf16x8 v = *(const bf16x8*)
            &Vr[(size_t)(b * L_ + st * 64 + s) * D_ + h * DH_ + dch * 8];
        #pragma unroll
        for (int e = 0; e < 8; ++e)
            T[dch * 8 + e][s] = v[e];
    }
    __syncthreads();
    #pragma unroll
    for (int k = 0; k < 2; ++k) {
        int c = k * 256 + t;
        int d = c >> 3, sch = c & 7;             // row d, 16B s-chunk
        bf16x8 v = *(const bf16x8*)&T[d][sch * 8];
        *(bf16x8*)&Vt[(((size_t)((b * H_ + h) * DH_ + d)) << 11)
                      + st * 64 + sch * 8] = v;
    }
}

// ---------------------------------------------------------------------------
// Flash attention, causal — swapped-QK^T 32x32x16, qt-paired load balance,
// log2-domain softmax, defer-max, K-row permutation (no PV exchange).
// UNCHANGED from R8 (verified, 104.8 us).
// ---------------------------------------------------------------------------
__device__ __forceinline__ u32 pack2(float a, float b) {
    union { u32 u; bf16_t h[2]; } p;
    p.h[0] = (bf16_t)a; p.h[1] = (bf16_t)b;
    return p.u;
}

__device__ __forceinline__ void stage_kv(
    const bf16_t* __restrict__ Kw, const bf16_t* __restrict__ Vt,
    bf16_t* kl, bf16_t* vl, int b, int h, int j0, int w, int l)
{
    #pragma unroll
    for (int q2 = 0; q2 < 2; ++q2) {
        int c  = q2 * 256 + w * 64 + l;      // 16B chunk id, 0..511
        int rr = c >> 3, kc = c & 7;         // row (128B = 8 chunks/row)
        int kcs = kc ^ (rr & 7);             // pre-swizzled global source chunk
        // K: LDS row rr holds key sigma(rr) = rr with bits 2,3 swapped
        int rs = (rr & ~12) | ((rr & 4) << 1) | ((rr & 8) >> 1);
        async_load16(&Kw[(size_t)(b * L_ + j0 + rs) * D_ + h * DH_ + kcs * 8],
                     &kl[(q2 * 256 + w * 64) * 8]);
        async_load16(&Vt[((size_t)((b * H_ + h) * DH_ + rr)) * (size_t)L_ + j0 + kcs * 8],
                     &vl[(q2 * 256 + w * 64) * 8]);
    }
}

__global__ __launch_bounds__(256) void attn_fwd(
    const bf16_t* __restrict__ Qw, const bf16_t* __restrict__ Kw,
    const bf16_t* __restrict__ Vt, bf16_t* __restrict__ Ow)
{
    __shared__ __align__(16) bf16_t k_lds[2][4096];  // 2 x 64(s) x 64(d), swz
    __shared__ __align__(16) bf16_t v_lds[2][4096];  // 2 x 64(d) x 64(s), swz
    __shared__ float l_scr[4][32];                   // per-wave redistribute

    const int t = threadIdx.x;
    const int w = t >> 6, l = t & 63;
    const int l31 = l & 31, hi = l >> 5;
    const int pr = blockIdx.x;                    // pair index 0..7
    const int h = blockIdx.y, b = blockIdx.z;

    #pragma unroll 1
    for (int pass = 0; pass < 2; ++pass) {
        const int qt = pass == 0 ? (15 - pr) : pr;    // heavy tile first
        const int qrow = qt * 128 + w * 32 + l31;     // this lane's query

        // Q fragments (B-operand), pre-scaled by 0.125*log2e (exp2 fold)
        bf16x8 bq[4];
        {
            const bf16_t* qp = Qw + (size_t)(b * L_ + qrow) * D_ + h * DH_ + hi * 8;
            #pragma unroll
            for (int kd = 0; kd < 4; ++kd) {
                bq[kd] = *(const bf16x8*)(qp + kd * 16);
                #pragma unroll
                for (int j = 0; j < 8; ++j)
                    bq[kd][j] = (bf16_t)((float)bq[kd][j] * 0.180336880f);
            }
        }

        f32x16 acc0 = {}, acc1 = {};   // O: reg=query-row, l31=d (acc1: d+32)
        float m_i = -1e30f, l_i = 0.f;

        stage_kv(Kw, Vt, k_lds[0], v_lds[0], b, h, 0, w, l);
        __syncthreads();

        const int nkt  = 2 * qt + 2;
        const int wmax = qt * 128 + w * 32 + 31;
        int cur = 0;
        for (int jt = 0; jt < nkt; ++jt) {
            if (jt + 1 < nkt)
                stage_kv(Kw, Vt, k_lds[cur ^ 1], v_lds[cur ^ 1], b, h, (jt + 1) * 64, w, l);

            const int j0 = jt * 64;
            if (j0 <= wmax) {             // wave-uniform: skip fully-masked tile
                // S^T = K * Q^T : s0 = key-positions 0..31, s1 = 32..63
                f32x16 s0 = {}, s1 = {};
                #pragma unroll
                for (int kd = 0; kd < 4; ++kd) {
                    int sw = ((kd * 2 + hi) ^ (l31 & 7)) * 8;   // same both rows
                    bf16x8 ak0 = *(const bf16x8*)&k_lds[cur][l31 * 64 + sw];
                    bf16x8 ak1 = *(const bf16x8*)&k_lds[cur][(32 + l31) * 64 + sw];
                    s0 = __builtin_amdgcn_mfma_f32_32x32x16_bf16(ak0, bq[kd], s0, 0, 0, 0);
                    s1 = __builtin_amdgcn_mfma_f32_32x32x16_bf16(ak1, bq[kd], s1, 0, 0, 0);
                }

                // causal mask — permuted key = (r&7) + 8*hi + 16*(r>>3)
                if (jt >= 2 * qt) {
                    #pragma unroll
                    for (int reg = 0; reg < 16; ++reg) {
                        int key = (reg & 7) + 8 * hi + 16 * (reg >> 3);
                        if (j0 + key > qrow)      s0[reg] = -1e30f;
                        if (j0 + 32 + key > qrow) s1[reg] = -1e30f;
                    }
                }

                // row max: local tree over 32 values + one cross-half combine
                float mt_[16];
                #pragma unroll
                for (int r = 0; r < 16; ++r) mt_[r] = fmaxf(s0[r], s1[r]);
                #pragma unroll
                for (int st = 8; st > 0; st >>= 1)
                    #pragma unroll
                    for (int r = 0; r < st; ++r) mt_[r] = fmaxf(mt_[r], mt_[r + st]);
                float mx = fmaxf(mt_[0], __shfl_xor(mt_[0], 32));

                // defer-max (T13): rescale only when the max actually grew
                int grew = !(mx <= m_i + 8.f);
                if (__any(grew)) {
                    float mn = fmaxf(m_i, mx);
                    float alpha = exp2f(m_i - mn);
                    m_i = mn; l_i *= alpha;
                    l_scr[w][l31] = alpha;     // both hi-halves write same value
                    asm volatile("s_waitcnt lgkmcnt(0)" ::: "memory");
                    #pragma unroll
                    for (int reg = 0; reg < 16; ++reg) {
                        int row = (reg & 3) + 8 * (reg >> 2) + 4 * hi;
                        float a2 = l_scr[w][row];          // broadcast read
                        acc0[reg] *= a2; acc1[reg] *= a2;
                    }
                }

                // p = exp2(s - m) in place; row sum tree + cross-half combine
                #pragma unroll
                for (int r = 0; r < 16; ++r) s0[r] = exp2f(s0[r] - m_i);
                #pragma unroll
                for (int r = 0; r < 16; ++r) s1[r] = exp2f(s1[r] - m_i);
                float st_[16];
                #pragma unroll
                for (int r = 0; r < 16; ++r) st_[r] = s0[r] + s1[r];
                #pragma unroll
                for (int st = 8; st > 0; st >>= 1)
                    #pragma unroll
                    for (int r = 0; r < st; ++r) st_[r] += st_[r + st];
                l_i += st_[0] + __shfl_xor(st_[0], 32);

                // PV: pa[ks] = own regs 8*(ks&1)..+7 of s0/s1 — no exchange.
                const float* e0p = (const float*)&s0;
                const float* e1p = (const float*)&s1;
                #pragma unroll
                for (int ks = 0; ks < 4; ++ks) {
                    const float* e = (ks < 2) ? e0p : e1p;
                    const int base = (ks & 1) * 8;
                    union { u32 uw[4]; bf16x8 v8; } pu;
                    pu.uw[0] = pack2(e[base + 0], e[base + 1]);
                    pu.uw[1] = pack2(e[base + 2], e[base + 3]);
                    pu.uw[2] = pack2(e[base + 4], e[base + 5]);
                    pu.uw[3] = pack2(e[base + 6], e[base + 7]);

                    int sw = ((ks * 2 + hi) ^ (l31 & 7)) * 8;
                    bf16x8 bv0 = *(const bf16x8*)&v_lds[cur][l31 * 64 + sw];
                    bf16x8 bv1 = *(const bf16x8*)&v_lds[cur][(32 + l31) * 64 + sw];
                    acc0 = __builtin_amdgcn_mfma_f32_32x32x16_bf16(pu.v8, bv0, acc0, 0, 0, 0);
                    acc1 = __builtin_amdgcn_mfma_f32_32x32x16_bf16(pu.v8, bv1, acc1, 0, 0, 0);
                }
            }

            __syncthreads();   // drains this iter's async stage; buf reuse
            cur ^= 1;
        }

        // final: redistribute l_i (query-indexed) to acc rows, divide, store
        l_scr[w][l31] = l_i;
        asm volatile("s_waitcnt lgkmcnt(0)" ::: "memory");
        #pragma unroll
        for (int reg = 0; reg < 16; ++reg) {
            int row = (reg & 3) + 8 * (reg >> 2) + 4 * hi;
            float inv = 1.f / l_scr[w][row];
            int grow = qt * 128 + w * 32 + row;
            size_t base = (size_t)(b * L_ + grow) * D_ + h * DH_ + l31;
            Ow[base]      = (bf16_t)(acc0[reg] * inv);
            Ow[base + 32] = (bf16_t)(acc1[reg] * inv);
        }
        // pass-1 staging is safe: every wave passed the loop's final
        // __syncthreads after its last LDS read; stores above are global-only.
    }
}

extern "C" void kernel_launch(void* const* d_in, const int* in_sizes, int n_in,
                              void* d_out, int out_size, void* d_ws, size_t ws_size,
                              hipStream_t stream)
{
    // Inputs fp32, output fp32. Compute in bf16 MFMA, final store fp32.
    const float* queries = (const float*)d_in[0];
    const float* keys    = (const float*)d_in[1];
    const float* values  = (const float*)d_in[2];
    const float* Wq = (const float*)d_in[3];
    const float* Wk = (const float*)d_in[4];
    const float* Wv = (const float*)d_in[5];
    const float* Wo = (const float*)d_in[6];
    float* out = (float*)d_out;

    const size_t SZ = (size_t)B_ * L_ * D_;   // 8,388,608
    const size_t WZ = (size_t)D_ * D_;        // 1,048,576
    bf16_t* cbuf  = (bf16_t*)d_ws;            // queries bf16; later Vt
    bf16_t* cWq   = cbuf + SZ;
    bf16_t* cWk   = cWq + WZ;
    bf16_t* cWv   = cWk + WZ;
    bf16_t* cWo   = cWv + WZ;
    bf16_t* q_ws  = cWo + WZ;
    bf16_t* k_ws  = q_ws + SZ;
    bf16_t* vt_ws = k_ws + SZ;                // V row-major; later attn out

    // keys/values bf16 scratch carved from d_out (dead until final GEMM).
    bf16_t* ck = (bf16_t*)d_out;
    bf16_t* cv = ck + SZ;

    cvt_all<<<28672, 256, 0, stream>>>(queries, keys, values, Wq, Wk, Wv, Wo,
                                       cbuf, ck, cv, cWq, cWk, cWv, cWo);

    // QKV projections: 512 persistent blocks (2/CU), z-sequenced for L2.
    gemm_qkv<<<dim3(8, 64), 256, 0, stream>>>(
        cbuf, cWq, q_ws,
        ck,   cWk, k_ws,
        cv,   cWv, vt_ws);

    // V [B*L][1024] -> Vt[B][H][64][2048] into cbuf (queries-bf16 now dead)
    transpose_v<<<dim3(32, H_, B_), 256, 0, stream>>>(vt_ws, cbuf);

    // attn reads Vt from cbuf, writes output into vt_ws (V rowmajor now dead)
    attn_fwd<<<dim3(8, H_, B_), 256, 0, stream>>>(q_ws, k_ws, cbuf, vt_ws);

    gemm_bt<<<dim3(8, 64), 256, 0, stream>>>(vt_ws, cWo, nullptr, out, 2);
}